// Round 2
// baseline (165.016 us; speedup 1.0000x reference)
//
#include <hip/hip_runtime.h>
#include <hip/hip_bf16.h>

typedef __attribute__((ext_vector_type(8))) short s16x8;
typedef __attribute__((ext_vector_type(4))) float f32x4;
typedef __attribute__((ext_vector_type(8))) unsigned short u16x8;
typedef __attribute__((ext_vector_type(4))) unsigned short u16x4;

static __device__ __forceinline__ unsigned short f2bf(float f) {
  unsigned int u = __float_as_uint(f);
  unsigned int r = u + 0x7fffu + ((u >> 16) & 1u);
  return (unsigned short)(r >> 16);
}
static __device__ __forceinline__ float bf2f(unsigned short s) {
  return __uint_as_float(((unsigned int)s) << 16);
}

static __device__ __forceinline__ void gload16(const void* g, void* l) {
  __builtin_amdgcn_global_load_lds(
      (const __attribute__((address_space(1))) unsigned int*)g,
      (__attribute__((address_space(3))) unsigned int*)l, 16, 0, 0);
}

// ---------------- small kernels ----------------

// proj_w fp32 (768*256) -> bf16, layout unchanged ((N=768, K=256) row-major)
__global__ void k_cvt(const float* __restrict__ in, unsigned short* __restrict__ o) {
  int i = blockIdx.x * 256 + threadIdx.x;  // 192*256 = 49152 float4s
  float4 v = reinterpret_cast<const float4*>(in)[i];
  u16x4 pk = { f2bf(v.x), f2bf(v.y), f2bf(v.z), f2bf(v.w) };
  reinterpret_cast<u16x4*>(o)[i] = pk;
}

// ctx_w (768x768) transpose -> cwT[f][e] = ctx_w[e][f]
__global__ void k_transpose768(const float* __restrict__ in, float* __restrict__ out) {
  __shared__ float tile[32][33];
  int bx = blockIdx.x % 24, by = blockIdx.x / 24;
  int tx = threadIdx.x & 31, ty = threadIdx.x >> 5;
#pragma unroll
  for (int k = 0; k < 4; ++k)
    tile[ty + 8 * k][tx] = in[(size_t)(by * 32 + ty + 8 * k) * 768 + bx * 32 + tx];
  __syncthreads();
#pragma unroll
  for (int k = 0; k < 4; ++k)
    out[(size_t)(bx * 32 + ty + 8 * k) * 768 + by * 32 + tx] = tile[tx][ty + 8 * k];
}

// One pass over x: emit patch-major bf16 copy xbf[bc*196+hp*14+wp][p*16+q]
// and per-(bc) average patch (mean over 196 patches) for the context path.
__global__ __launch_bounds__(256) void k_prep(const float* __restrict__ x,
                                              unsigned short* __restrict__ xbf,
                                              float* __restrict__ avg) {
  __shared__ __align__(16) unsigned short strip[14 * 256];  // one hp-strip, 7 KB
  int bc = blockIdx.x;
  int t = threadIdx.x;
  const float* img = x + (size_t)bc * 224 * 224;
  unsigned short* orow = xbf + (size_t)bc * 196 * 256;
  float acc = 0.f;

  for (int hp = 0; hp < 14; ++hp) {
    __syncthreads();  // previous strip consumed
    // load 16 rows x 224 floats = 896 float4, convert, scatter to patch layout
    for (int idx = t; idx < 896; idx += 256) {
      int row = idx / 56, c4 = idx - row * 56;
      float4 v = reinterpret_cast<const float4*>(img + (size_t)(hp * 16 + row) * 224)[c4];
      int wp = c4 >> 2, q0 = (c4 & 3) << 2;
      u16x4 pk = { f2bf(v.x), f2bf(v.y), f2bf(v.z), f2bf(v.w) };
      *(u16x4*)&strip[wp * 256 + row * 16 + q0] = pk;
    }
    __syncthreads();
    // accumulate avg over this strip's 14 patches (thread t == k)
#pragma unroll
    for (int wp = 0; wp < 14; ++wp) acc += bf2f(strip[wp * 256 + t]);
    // write strip out (contiguous 7168 B)
    {
      const u16x8* so = (const u16x8*)strip;
      u16x8* go = (u16x8*)(orow + hp * 3584);
      for (int i = t; i < 448; i += 256) go[i] = so[i];
    }
  }
  avg[bc * 256 + t] = acc * (1.0f / 196.0f);
}

// fused context chain: per-segment mean -> proj -> ctx projection
// addv[s][e] = ctx(mean_patch(s) @ projW + pb) + cb + pb
__global__ __launch_bounds__(768) void k_chain(const float* __restrict__ avg,
                                               const int* __restrict__ seg,
                                               const float* __restrict__ pw,
                                               const float* __restrict__ pb,
                                               const float* __restrict__ cwT,
                                               const float* __restrict__ cb,
                                               float* __restrict__ addv) {
  __shared__ float sp[256];
  __shared__ float mn[768];
  __shared__ int ssg[256];
  int s = blockIdx.x, t = threadIdx.x;
  if (t < 256) ssg[t] = seg[t];
  __syncthreads();
  if (t < 256) {
    float sum = 0.f; int c = 0;
    for (int bc = 0; bc < 256; ++bc)
      if (ssg[bc] == s) { sum += avg[bc * 256 + t]; ++c; }
    sp[t] = sum / (float)(c > 0 ? c : 1);
  }
  __syncthreads();
  {
    const float4* w = reinterpret_cast<const float4*>(pw + (size_t)t * 256);
    float a = 0.f;
#pragma unroll 8
    for (int k = 0; k < 64; ++k) {
      float4 v = w[k];
      a += v.x * sp[k * 4] + v.y * sp[k * 4 + 1] + v.z * sp[k * 4 + 2] + v.w * sp[k * 4 + 3];
    }
    mn[t] = a + pb[t];
  }
  __syncthreads();
  float a2 = 0.f;
#pragma unroll 8
  for (int f = 0; f < 768; ++f) a2 += mn[f] * cwT[(size_t)f * 768 + t];
  addv[s * 768 + t] = a2 + cb[t] + pb[t];
}

// ---------------- main GEMM (bf16 A from xbf, global_load_lds both operands) ----
// C[50176][768] = xbf(M,256) x pwbf^T(256,768); epilogue += addv[seg[M/196]][n]
// BM=BN=128, BK=64, 4 waves (2x2, 64x64), mfma 16x16x32 bf16.
// LDS linear [128][128B] with st-swizzle realized by pre-swizzling the GLOBAL
// source per lane (global_load_lds writes linearly): slot ^= row&7.
__global__ __launch_bounds__(256) void k_gemm(
    const unsigned short* __restrict__ xbf, const unsigned short* __restrict__ wbf,
    const float* __restrict__ addv, const int* __restrict__ seg,
    float* __restrict__ out) {
  __shared__ __align__(16) unsigned short Al[128 * 64];  // 16 KB
  __shared__ __align__(16) unsigned short Bl[128 * 64];  // 16 KB

  int bid = blockIdx.x;
  int xcd = bid & 7, local = bid >> 3;
  int mb = xcd * 49 + local / 6;
  int nb = local - (local / 6) * 6;
  int m0 = mb << 7, n0 = nb << 7;

  int t = threadIdx.x;
  int wave = t >> 6, lane = t & 63;
  int wm = (wave >> 1) << 6, wn = (wave & 1) << 6;
  int lr = lane & 15, hi = lane >> 4;
  int axor = (lr & 7) << 4;

  // staging: issue i of wave w covers LDS bytes (w*4+i)*1024 = rows 8(w*4+i)..+7.
  // lane l -> row 8g + l/8, phys slot l%8; logical col byte = 16*((l&7)^((l>>3)&7))
  int swz = (((lane & 7) ^ ((lane >> 3) & 7)) << 4);
  const char* abase = (const char*)xbf + (size_t)(m0 + (lane >> 3)) * 512 + swz + (size_t)wave * 16384;
  const char* bbase = (const char*)wbf + (size_t)(n0 + (lane >> 3)) * 512 + swz + (size_t)wave * 16384;
  char* adst = (char*)Al + wave * 4096;
  char* bdst = (char*)Bl + wave * 4096;
  const char* Alc = (const char*)Al;
  const char* Blc = (const char*)Bl;

  f32x4 acc[4][4] = {};

  for (int kt = 0; kt < 4; ++kt) {
#pragma unroll
    for (int i = 0; i < 4; ++i) {
      gload16(abase + kt * 128 + i * 4096, adst + i * 1024);
      gload16(bbase + kt * 128 + i * 4096, bdst + i * 1024);
    }
    __syncthreads();  // drains vmcnt (gload_lds) + lgkm
#pragma unroll
    for (int kk = 0; kk < 2; ++kk) {
      s16x8 af[4], bv[4];
      int koff = kk * 64 + hi * 16;
#pragma unroll
      for (int i = 0; i < 4; ++i)
        af[i] = *(const s16x8*)(Alc + (wm + i * 16 + lr) * 128 + (koff ^ axor));
#pragma unroll
      for (int j = 0; j < 4; ++j)
        bv[j] = *(const s16x8*)(Blc + (wn + j * 16 + lr) * 128 + (koff ^ axor));
#pragma unroll
      for (int i = 0; i < 4; ++i)
#pragma unroll
        for (int j = 0; j < 4; ++j)
          acc[i][j] = __builtin_amdgcn_mfma_f32_16x16x32_bf16(af[i], bv[j], acc[i][j], 0, 0, 0);
    }
    __syncthreads();  // before next stage overwrites
  }

  // epilogue: out[M][n] = acc + addv[seg[M/196]][n]
#pragma unroll
  for (int i = 0; i < 4; ++i) {
    int mloc = m0 + wm + i * 16 + (hi << 2);
#pragma unroll
    for (int r = 0; r < 4; ++r) {
      int M = mloc + r;
      int sgi = seg[M / 196];
      const float* av = addv + (size_t)sgi * 768 + n0 + wn + lr;
      float* orow = out + (size_t)M * 768 + n0 + wn + lr;
#pragma unroll
      for (int j = 0; j < 4; ++j)
        orow[j * 16] = acc[i][j][r] + av[j * 16];
    }
  }
}

// ---------------- fallback GEMM (v1, fp32-source) if ws too small ----------------
__global__ void k_avgpatch_fb(const float* __restrict__ x, float* __restrict__ avg) {
  int bc = blockIdx.x;
  int k = threadIdx.x;
  int p = k >> 4, q = k & 15;
  const float* base = x + (size_t)bc * 224 * 224;
  float s = 0.f;
  for (int hp = 0; hp < 14; ++hp) {
    const float* row = base + (hp * 16 + p) * 224 + q;
#pragma unroll
    for (int wp = 0; wp < 14; ++wp) s += row[wp * 16];
  }
  avg[bc * 256 + k] = s * (1.0f / 196.0f);
}

__global__ __launch_bounds__(256) void k_gemm_fb(
    const float* __restrict__ x, const unsigned short* __restrict__ wbf,
    const float* __restrict__ addv, const int* __restrict__ seg,
    float* __restrict__ out) {
  __shared__ unsigned short Al[128][40];
  __shared__ unsigned short Bl[128][40];
  int bid = blockIdx.x;
  int xcd = bid & 7, local = bid >> 3;
  int mb = xcd * 49 + local / 6;
  int nb = local - (local / 6) * 6;
  int m0 = mb << 7, n0 = nb << 7;
  int t = threadIdx.x;
  int wave = t >> 6, lane = t & 63;
  int wm = (wave >> 1) << 6, wn = (wave & 1) << 6;
  int lr = lane & 15, lk = (lane >> 4) << 3;
  int mstage = m0 + (t >> 1);
  int halfA = t & 1;
  int bc = mstage / 196;
  int pij = mstage - bc * 196;
  int hp = pij / 14;
  int wp = pij - hp * 14;
  const float* xbase = x + ((size_t)bc * 224 + hp * 16 + halfA) * 224 + wp * 16;
  const unsigned short* bsrc = wbf + (size_t)(n0 + (t >> 1)) * 256 + halfA * 16;
  unsigned short* adst = &Al[t >> 1][halfA * 16];
  unsigned short* bdst = &Bl[t >> 1][halfA * 16];
  f32x4 acc[4][4] = {};
  for (int ks = 0; ks < 8; ++ks) {
    __syncthreads();
    *(u16x8*)bdst       = *(const u16x8*)(bsrc + ks * 32);
    *(u16x8*)(bdst + 8) = *(const u16x8*)(bsrc + ks * 32 + 8);
    {
      const float4* src = reinterpret_cast<const float4*>(xbase + ks * 448);
      float4 v0 = src[0], v1 = src[1], v2 = src[2], v3 = src[3];
      u16x8 p0 = { f2bf(v0.x), f2bf(v0.y), f2bf(v0.z), f2bf(v0.w),
                   f2bf(v1.x), f2bf(v1.y), f2bf(v1.z), f2bf(v1.w) };
      u16x8 p1 = { f2bf(v2.x), f2bf(v2.y), f2bf(v2.z), f2bf(v2.w),
                   f2bf(v3.x), f2bf(v3.y), f2bf(v3.z), f2bf(v3.w) };
      *(u16x8*)adst = p0;
      *(u16x8*)(adst + 8) = p1;
    }
    __syncthreads();
    s16x8 af[4], bfv[4];
#pragma unroll
    for (int i = 0; i < 4; ++i) af[i] = *(const s16x8*)&Al[wm + i * 16 + lr][lk];
#pragma unroll
    for (int j = 0; j < 4; ++j) bfv[j] = *(const s16x8*)&Bl[wn + j * 16 + lr][lk];
#pragma unroll
    for (int i = 0; i < 4; ++i)
#pragma unroll
      for (int j = 0; j < 4; ++j)
        acc[i][j] = __builtin_amdgcn_mfma_f32_16x16x32_bf16(af[i], bfv[j], acc[i][j], 0, 0, 0);
  }
#pragma unroll
  for (int i = 0; i < 4; ++i) {
    int mloc = m0 + wm + i * 16 + ((lane >> 4) << 2);
#pragma unroll
    for (int r = 0; r < 4; ++r) {
      int M = mloc + r;
      int sgi = seg[M / 196];
      const float* av = addv + (size_t)sgi * 768 + n0 + wn + lr;
      float* orow = out + (size_t)M * 768 + n0 + wn + lr;
#pragma unroll
      for (int j = 0; j < 4; ++j)
        orow[j * 16] = acc[i][j][r] + av[j * 16];
    }
  }
}

// ---------------- launch ----------------

extern "C" void kernel_launch(void* const* d_in, const int* in_sizes, int n_in,
                              void* d_out, int out_size, void* d_ws, size_t ws_size,
                              hipStream_t stream) {
  (void)in_sizes; (void)n_in; (void)out_size;
  const float* x  = (const float*)d_in[0];
  const int*   sg = (const int*)d_in[1];
  const float* pw = (const float*)d_in[2];
  const float* pb = (const float*)d_in[3];
  const float* cw = (const float*)d_in[4];
  const float* cb = (const float*)d_in[5];
  float* out = (float*)d_out;

  char* ws = (char*)d_ws;
  unsigned short* pwbf = (unsigned short*)ws;            // 393216 B
  float* avgp  = (float*)(ws + 393216);                  // 262144 B
  float* cwT   = (float*)(ws + 655360);                  // 2359296 B
  float* addv  = (float*)(ws + 3014656);                 // 98304 B
  unsigned short* xbf = (unsigned short*)(ws + 3112960); // 25690112 B
  const size_t NEED = 3112960u + 25690112u;              // 28.8 MB

  k_cvt<<<192, 256, 0, stream>>>(pw, pwbf);
  k_transpose768<<<576, 256, 0, stream>>>(cw, cwT);
  if (ws_size >= NEED) {
    k_prep<<<256, 256, 0, stream>>>(x, xbf, avgp);
    k_chain<<<32, 768, 0, stream>>>(avgp, sg, pw, pb, cwT, cb, addv);
    k_gemm<<<2352, 256, 0, stream>>>(xbf, pwbf, addv, sg, out);
  } else {
    k_avgpatch_fb<<<256, 256, 0, stream>>>(x, avgp);
    k_chain<<<32, 768, 0, stream>>>(avgp, sg, pw, pb, cwT, cb, addv);
    k_gemm_fb<<<2352, 256, 0, stream>>>(x, pwbf, addv, sg, out);
  }
}

// Round 3
// 101.604 us; speedup vs baseline: 1.6241x; 1.6241x over previous
//
#include <hip/hip_runtime.h>
#include <hip/hip_bf16.h>

typedef __attribute__((ext_vector_type(8))) short s16x8;
typedef __attribute__((ext_vector_type(4))) float f32x4;
typedef __attribute__((ext_vector_type(8))) unsigned short u16x8;
typedef __attribute__((ext_vector_type(4))) unsigned short u16x4;

static __device__ __forceinline__ unsigned short f2bf(float f) {
  unsigned int u = __float_as_uint(f);
  unsigned int r = u + 0x7fffu + ((u >> 16) & 1u);
  return (unsigned short)(r >> 16);
}
static __device__ __forceinline__ float bf2f(unsigned short s) {
  return __uint_as_float(((unsigned int)s) << 16);
}

static __device__ __forceinline__ void gload16(const void* g, void* l) {
  __builtin_amdgcn_global_load_lds(
      (const __attribute__((address_space(1))) unsigned int*)g,
      (__attribute__((address_space(3))) unsigned int*)l, 16, 0, 0);
}

// ---------------- small kernels ----------------

// proj_w fp32 (768*256) -> bf16, layout unchanged ((N=768, K=256) row-major)
__global__ void k_cvt(const float* __restrict__ in, unsigned short* __restrict__ o) {
  int i = blockIdx.x * 256 + threadIdx.x;  // 192*256 = 49152 float4s
  float4 v = reinterpret_cast<const float4*>(in)[i];
  u16x4 pk = { f2bf(v.x), f2bf(v.y), f2bf(v.z), f2bf(v.w) };
  reinterpret_cast<u16x4*>(o)[i] = pk;
}

// ctx_w (768x768) transpose -> cwT[f][e] = ctx_w[e][f]
__global__ void k_transpose768(const float* __restrict__ in, float* __restrict__ out) {
  __shared__ float tile[32][33];
  int bx = blockIdx.x % 24, by = blockIdx.x / 24;
  int tx = threadIdx.x & 31, ty = threadIdx.x >> 5;
#pragma unroll
  for (int k = 0; k < 4; ++k)
    tile[ty + 8 * k][tx] = in[(size_t)(by * 32 + ty + 8 * k) * 768 + bx * 32 + tx];
  __syncthreads();
#pragma unroll
  for (int k = 0; k < 4; ++k)
    out[(size_t)(bx * 32 + ty + 8 * k) * 768 + by * 32 + tx] = tile[tx][ty + 8 * k];
}

// One strip (16 rows) per block: emit patch-major bf16 to xbf and the
// per-(bc,hp) partial patch-sum (NOT yet /196) to avg3[(bc*14+hp)*256+k].
// grid 3584 = 256 images x 14 strips -> ~14 blocks/CU.
__global__ __launch_bounds__(256) void k_prep(const float* __restrict__ x,
                                              unsigned short* __restrict__ xbf,
                                              float* __restrict__ avg3) {
  __shared__ __align__(16) unsigned short strip[14 * 256];  // 7 KB
  int b = blockIdx.x;
  int bc = b / 14, hp = b - bc * 14;
  int t = threadIdx.x;
  const float* img = x + ((size_t)bc * 224 + hp * 16) * 224;

  for (int idx = t; idx < 896; idx += 256) {
    int row = idx / 56, c4 = idx - row * 56;
    float4 v = reinterpret_cast<const float4*>(img + (size_t)row * 224)[c4];
    int wp = c4 >> 2, q0 = (c4 & 3) << 2;
    u16x4 pk = { f2bf(v.x), f2bf(v.y), f2bf(v.z), f2bf(v.w) };
    *(u16x4*)&strip[wp * 256 + row * 16 + q0] = pk;
  }
  __syncthreads();

  float acc = 0.f;
#pragma unroll
  for (int wp = 0; wp < 14; ++wp) acc += bf2f(strip[wp * 256 + t]);
  avg3[((size_t)bc * 14 + hp) * 256 + t] = acc;

  const u16x8* so = (const u16x8*)strip;
  u16x8* go = (u16x8*)(xbf + ((size_t)bc * 196 + hp * 14) * 256);
  for (int i = t; i < 448; i += 256) go[i] = so[i];
}

// sp[s][k] = (sum over bc with seg[bc]==s, hp of avg3[bc*14+hp][k]) / (196*max(cnt,1))
// grid 128 = 32 segments x 4 k-chunks; 256 threads = 64 k x 4 bc-slices.
__global__ __launch_bounds__(256) void k_segmean(const float* __restrict__ avg3,
                                                 const int* __restrict__ seg,
                                                 float* __restrict__ sp) {
  __shared__ float red[4][64];
  __shared__ int rcnt[4];
  __shared__ int ssg[256];
  int s = blockIdx.x & 31, kc = blockIdx.x >> 5;
  int t = threadIdx.x;
  int kl = t & 63, slice = t >> 6;
  int k = kc * 64 + kl;
  ssg[t] = seg[t];
  __syncthreads();
  float sum = 0.f; int cnt = 0;
  for (int bc = slice * 64; bc < slice * 64 + 64; ++bc) {
    if (ssg[bc] == s) {
      ++cnt;
      const float* row = avg3 + (size_t)bc * 14 * 256 + k;
#pragma unroll
      for (int hp = 0; hp < 14; ++hp) sum += row[hp * 256];
    }
  }
  red[slice][kl] = sum;
  if (kl == 0) rcnt[slice] = cnt;
  __syncthreads();
  if (t < 64) {
    float tot = red[0][t] + red[1][t] + red[2][t] + red[3][t];
    int c = rcnt[0] + rcnt[1] + rcnt[2] + rcnt[3];
    sp[s * 256 + kc * 64 + t] = tot / (196.0f * (float)(c > 0 ? c : 1));
  }
}

// means[s][e] = sp[s] . pw[e] + pb[e]; grid 768 = 32 s x 24 e-chunks(32);
// 256 threads = 32 e x 8 k-slices(32)
__global__ __launch_bounds__(256) void k_means2(const float* __restrict__ sp,
                                                const float* __restrict__ pw,
                                                const float* __restrict__ pb,
                                                float* __restrict__ means) {
  __shared__ float ssp[256];
  __shared__ float red[8][32];
  int s = blockIdx.x & 31, e0 = (blockIdx.x >> 5) << 5;
  int t = threadIdx.x;
  int e = t & 31, ksl = t >> 5;
  ssp[t] = sp[s * 256 + t];
  __syncthreads();
  const float4* w = reinterpret_cast<const float4*>(pw + (size_t)(e0 + e) * 256 + ksl * 32);
  float a = 0.f;
#pragma unroll
  for (int j = 0; j < 8; ++j) {
    float4 v = w[j];
    int kb = ksl * 32 + j * 4;
    a += v.x * ssp[kb] + v.y * ssp[kb + 1] + v.z * ssp[kb + 2] + v.w * ssp[kb + 3];
  }
  red[ksl][e] = a;
  __syncthreads();
  if (t < 32) {
    float tot = 0.f;
#pragma unroll
    for (int j = 0; j < 8; ++j) tot += red[j][t];
    means[s * 768 + e0 + t] = tot + pb[e0 + t];
  }
}

// addv[s][e] = means[s] . cwT[:,e] + cb[e] + pb[e]; grid 768 = 32 s x 24 e-chunks;
// 256 threads = 32 e x 8 f-slices(96); cwT[f][e] reads coalesced across e.
__global__ __launch_bounds__(256) void k_ctx2(const float* __restrict__ means,
                                              const float* __restrict__ cwT,
                                              const float* __restrict__ cb,
                                              const float* __restrict__ pb,
                                              float* __restrict__ addv) {
  __shared__ float mn[768];
  __shared__ float red[8][32];
  int s = blockIdx.x & 31, e0 = (blockIdx.x >> 5) << 5;
  int t = threadIdx.x;
  int e = t & 31, fsl = t >> 5;
  mn[t] = means[s * 768 + t];
  mn[t + 256] = means[s * 768 + 256 + t];
  mn[t + 512] = means[s * 768 + 512 + t];
  __syncthreads();
  const float* col = cwT + (size_t)fsl * 96 * 768 + e0 + e;
  float a = 0.f;
#pragma unroll 8
  for (int j = 0; j < 96; ++j) a += mn[fsl * 96 + j] * col[(size_t)j * 768];
  red[fsl][e] = a;
  __syncthreads();
  if (t < 32) {
    float tot = 0.f;
#pragma unroll
    for (int j = 0; j < 8; ++j) tot += red[j][t];
    addv[s * 768 + e0 + t] = tot + cb[e0 + t] + pb[e0 + t];
  }
}

// ---------------- main GEMM (unchanged from round 2, passing) ----------------
__global__ __launch_bounds__(256) void k_gemm(
    const unsigned short* __restrict__ xbf, const unsigned short* __restrict__ wbf,
    const float* __restrict__ addv, const int* __restrict__ seg,
    float* __restrict__ out) {
  __shared__ __align__(16) unsigned short Al[128 * 64];  // 16 KB
  __shared__ __align__(16) unsigned short Bl[128 * 64];  // 16 KB

  int bid = blockIdx.x;
  int xcd = bid & 7, local = bid >> 3;
  int mb = xcd * 49 + local / 6;
  int nb = local - (local / 6) * 6;
  int m0 = mb << 7, n0 = nb << 7;

  int t = threadIdx.x;
  int wave = t >> 6, lane = t & 63;
  int wm = (wave >> 1) << 6, wn = (wave & 1) << 6;
  int lr = lane & 15, hi = lane >> 4;
  int axor = (lr & 7) << 4;

  int swz = (((lane & 7) ^ ((lane >> 3) & 7)) << 4);
  const char* abase = (const char*)xbf + (size_t)(m0 + (lane >> 3)) * 512 + swz + (size_t)wave * 16384;
  const char* bbase = (const char*)wbf + (size_t)(n0 + (lane >> 3)) * 512 + swz + (size_t)wave * 16384;
  char* adst = (char*)Al + wave * 4096;
  char* bdst = (char*)Bl + wave * 4096;
  const char* Alc = (const char*)Al;
  const char* Blc = (const char*)Bl;

  f32x4 acc[4][4] = {};

  for (int kt = 0; kt < 4; ++kt) {
#pragma unroll
    for (int i = 0; i < 4; ++i) {
      gload16(abase + kt * 128 + i * 4096, adst + i * 1024);
      gload16(bbase + kt * 128 + i * 4096, bdst + i * 1024);
    }
    __syncthreads();
#pragma unroll
    for (int kk = 0; kk < 2; ++kk) {
      s16x8 af[4], bv[4];
      int koff = kk * 64 + hi * 16;
#pragma unroll
      for (int i = 0; i < 4; ++i)
        af[i] = *(const s16x8*)(Alc + (wm + i * 16 + lr) * 128 + (koff ^ axor));
#pragma unroll
      for (int j = 0; j < 4; ++j)
        bv[j] = *(const s16x8*)(Blc + (wn + j * 16 + lr) * 128 + (koff ^ axor));
#pragma unroll
      for (int i = 0; i < 4; ++i)
#pragma unroll
        for (int j = 0; j < 4; ++j)
          acc[i][j] = __builtin_amdgcn_mfma_f32_16x16x32_bf16(af[i], bv[j], acc[i][j], 0, 0, 0);
    }
    __syncthreads();
  }

#pragma unroll
  for (int i = 0; i < 4; ++i) {
    int mloc = m0 + wm + i * 16 + (hi << 2);
#pragma unroll
    for (int r = 0; r < 4; ++r) {
      int M = mloc + r;
      int sgi = seg[M / 196];
      const float* av = addv + (size_t)sgi * 768 + n0 + wn + lr;
      float* orow = out + (size_t)M * 768 + n0 + wn + lr;
#pragma unroll
      for (int j = 0; j < 4; ++j)
        orow[j * 16] = acc[i][j][r] + av[j * 16];
    }
  }
}

// ---------------- fallback path (round-1 style) if ws too small ----------------
__global__ void k_avgpatch_fb(const float* __restrict__ x, float* __restrict__ avg) {
  int bc = blockIdx.x;
  int k = threadIdx.x;
  int p = k >> 4, q = k & 15;
  const float* base = x + (size_t)bc * 224 * 224;
  float s = 0.f;
  for (int hp = 0; hp < 14; ++hp) {
    const float* row = base + (hp * 16 + p) * 224 + q;
#pragma unroll
    for (int wp = 0; wp < 14; ++wp) s += row[wp * 16];
  }
  avg[bc * 256 + k] = s * (1.0f / 196.0f);
}

__global__ __launch_bounds__(768) void k_chain_fb(const float* __restrict__ avg,
                                                  const int* __restrict__ seg,
                                                  const float* __restrict__ pw,
                                                  const float* __restrict__ pb,
                                                  const float* __restrict__ cwT,
                                                  const float* __restrict__ cb,
                                                  float* __restrict__ addv) {
  __shared__ float sp[256];
  __shared__ float mn[768];
  __shared__ int ssg[256];
  int s = blockIdx.x, t = threadIdx.x;
  if (t < 256) ssg[t] = seg[t];
  __syncthreads();
  if (t < 256) {
    float sum = 0.f; int c = 0;
    for (int bc = 0; bc < 256; ++bc)
      if (ssg[bc] == s) { sum += avg[bc * 256 + t]; ++c; }
    sp[t] = sum / (float)(c > 0 ? c : 1);
  }
  __syncthreads();
  {
    const float4* w = reinterpret_cast<const float4*>(pw + (size_t)t * 256);
    float a = 0.f;
#pragma unroll 8
    for (int k = 0; k < 64; ++k) {
      float4 v = w[k];
      a += v.x * sp[k * 4] + v.y * sp[k * 4 + 1] + v.z * sp[k * 4 + 2] + v.w * sp[k * 4 + 3];
    }
    mn[t] = a + pb[t];
  }
  __syncthreads();
  float a2 = 0.f;
#pragma unroll 8
  for (int f = 0; f < 768; ++f) a2 += mn[f] * cwT[(size_t)f * 768 + t];
  addv[s * 768 + t] = a2 + cb[t] + pb[t];
}

__global__ __launch_bounds__(256) void k_gemm_fb(
    const float* __restrict__ x, const unsigned short* __restrict__ wbf,
    const float* __restrict__ addv, const int* __restrict__ seg,
    float* __restrict__ out) {
  __shared__ unsigned short Al[128][40];
  __shared__ unsigned short Bl[128][40];
  int bid = blockIdx.x;
  int xcd = bid & 7, local = bid >> 3;
  int mb = xcd * 49 + local / 6;
  int nb = local - (local / 6) * 6;
  int m0 = mb << 7, n0 = nb << 7;
  int t = threadIdx.x;
  int wave = t >> 6, lane = t & 63;
  int wm = (wave >> 1) << 6, wn = (wave & 1) << 6;
  int lr = lane & 15, lk = (lane >> 4) << 3;
  int mstage = m0 + (t >> 1);
  int halfA = t & 1;
  int bc = mstage / 196;
  int pij = mstage - bc * 196;
  int hp = pij / 14;
  int wp = pij - hp * 14;
  const float* xbase = x + ((size_t)bc * 224 + hp * 16 + halfA) * 224 + wp * 16;
  const unsigned short* bsrc = wbf + (size_t)(n0 + (t >> 1)) * 256 + halfA * 16;
  unsigned short* adst = &Al[t >> 1][halfA * 16];
  unsigned short* bdst = &Bl[t >> 1][halfA * 16];
  f32x4 acc[4][4] = {};
  for (int ks = 0; ks < 8; ++ks) {
    __syncthreads();
    *(u16x8*)bdst       = *(const u16x8*)(bsrc + ks * 32);
    *(u16x8*)(bdst + 8) = *(const u16x8*)(bsrc + ks * 32 + 8);
    {
      const float4* src = reinterpret_cast<const float4*>(xbase + ks * 448);
      float4 v0 = src[0], v1 = src[1], v2 = src[2], v3 = src[3];
      u16x8 p0 = { f2bf(v0.x), f2bf(v0.y), f2bf(v0.z), f2bf(v0.w),
                   f2bf(v1.x), f2bf(v1.y), f2bf(v1.z), f2bf(v1.w) };
      u16x8 p1 = { f2bf(v2.x), f2bf(v2.y), f2bf(v2.z), f2bf(v2.w),
                   f2bf(v3.x), f2bf(v3.y), f2bf(v3.z), f2bf(v3.w) };
      *(u16x8*)adst = p0;
      *(u16x8*)(adst + 8) = p1;
    }
    __syncthreads();
    s16x8 af[4], bfv[4];
#pragma unroll
    for (int i = 0; i < 4; ++i) af[i] = *(const s16x8*)&Al[wm + i * 16 + lr][lk];
#pragma unroll
    for (int j = 0; j < 4; ++j) bfv[j] = *(const s16x8*)&Bl[wn + j * 16 + lr][lk];
#pragma unroll
    for (int i = 0; i < 4; ++i)
#pragma unroll
      for (int j = 0; j < 4; ++j)
        acc[i][j] = __builtin_amdgcn_mfma_f32_16x16x32_bf16(af[i], bfv[j], acc[i][j], 0, 0, 0);
  }
#pragma unroll
  for (int i = 0; i < 4; ++i) {
    int mloc = m0 + wm + i * 16 + ((lane >> 4) << 2);
#pragma unroll
    for (int r = 0; r < 4; ++r) {
      int M = mloc + r;
      int sgi = seg[M / 196];
      const float* av = addv + (size_t)sgi * 768 + n0 + wn + lr;
      float* orow = out + (size_t)M * 768 + n0 + wn + lr;
#pragma unroll
      for (int j = 0; j < 4; ++j)
        orow[j * 16] = acc[i][j][r] + av[j * 16];
    }
  }
}

// ---------------- launch ----------------

extern "C" void kernel_launch(void* const* d_in, const int* in_sizes, int n_in,
                              void* d_out, int out_size, void* d_ws, size_t ws_size,
                              hipStream_t stream) {
  (void)in_sizes; (void)n_in; (void)out_size;
  const float* x  = (const float*)d_in[0];
  const int*   sg = (const int*)d_in[1];
  const float* pw = (const float*)d_in[2];
  const float* pb = (const float*)d_in[3];
  const float* cw = (const float*)d_in[4];
  const float* cb = (const float*)d_in[5];
  float* out = (float*)d_out;

  char* ws = (char*)d_ws;
  unsigned short* pwbf = (unsigned short*)ws;            // 393216 B
  float* cwT   = (float*)(ws + 393216);                  // 2359296 B
  float* addv  = (float*)(ws + 2752512);                 // 98304 B
  float* sp    = (float*)(ws + 2850816);                 // 32768 B
  float* means = (float*)(ws + 2883584);                 // 98304 B
  float* avg3  = (float*)(ws + 2981888);                 // 3670016 B
  unsigned short* xbf = (unsigned short*)(ws + 6651904); // 25690112 B
  const size_t NEED = 6651904u + 25690112u;              // 32.3 MB

  k_cvt<<<192, 256, 0, stream>>>(pw, pwbf);
  k_transpose768<<<576, 256, 0, stream>>>(cw, cwT);
  if (ws_size >= NEED) {
    k_prep<<<3584, 256, 0, stream>>>(x, xbf, avg3);
    k_segmean<<<128, 256, 0, stream>>>(avg3, sg, sp);
    k_means2<<<768, 256, 0, stream>>>(sp, pw, pb, means);
    k_ctx2<<<768, 256, 0, stream>>>(means, cwT, cb, pb, addv);
    k_gemm<<<2352, 256, 0, stream>>>(xbf, pwbf, addv, sg, out);
  } else {
    float* avgp = (float*)(ws + 2981888);  // reuse avg3 slot, 262144 B
    k_avgpatch_fb<<<256, 256, 0, stream>>>(x, avgp);
    k_chain_fb<<<32, 768, 0, stream>>>(avgp, sg, pw, pb, cwT, cb, addv);
    k_gemm_fb<<<2352, 256, 0, stream>>>(x, pwbf, addv, sg, out);
  }
}

// Round 4
// 87.865 us; speedup vs baseline: 1.8781x; 1.1564x over previous
//
#include <hip/hip_runtime.h>
#include <hip/hip_bf16.h>

typedef __attribute__((ext_vector_type(8))) short s16x8;
typedef __attribute__((ext_vector_type(4))) float f32x4;
typedef __attribute__((ext_vector_type(8))) unsigned short u16x8;
typedef __attribute__((ext_vector_type(4))) unsigned short u16x4;

static __device__ __forceinline__ unsigned short f2bf(float f) {
  unsigned int u = __float_as_uint(f);
  unsigned int r = u + 0x7fffu + ((u >> 16) & 1u);
  return (unsigned short)(r >> 16);
}
static __device__ __forceinline__ float bf2f(unsigned short s) {
  return __uint_as_float(((unsigned int)s) << 16);
}

static __device__ __forceinline__ void gload16(const void* g, void* l) {
  __builtin_amdgcn_global_load_lds(
      (const __attribute__((address_space(1))) unsigned int*)g,
      (__attribute__((address_space(3))) unsigned int*)l, 16, 0, 0);
}

// ---------------- fused pre-pass ----------------
// blocks [0,3584): patchify strip -> xbf (bf16) + per-(bc,hp) partial sums
// blocks [3584,3776): proj_w fp32 -> bf16
// blocks [3776,4352): ctx_w transpose -> cwT
__global__ __launch_bounds__(256) void k_mega(const float* __restrict__ x,
                                              unsigned short* __restrict__ xbf,
                                              float* __restrict__ avg3,
                                              const float* __restrict__ pw,
                                              unsigned short* __restrict__ pwbf,
                                              const float* __restrict__ cw,
                                              float* __restrict__ cwT) {
  __shared__ __align__(16) char smem[7168];
  int b = blockIdx.x, t = threadIdx.x;
  if (b < 3584) {
    unsigned short* strip = (unsigned short*)smem;  // 14 patches x 256 = 7 KB
    int bc = b / 14, hp = b - bc * 14;
    const float* img = x + ((size_t)bc * 224 + hp * 16) * 224;
    for (int idx = t; idx < 896; idx += 256) {
      int row = idx / 56, c4 = idx - row * 56;
      float4 v = reinterpret_cast<const float4*>(img + (size_t)row * 224)[c4];
      int wp = c4 >> 2, q0 = (c4 & 3) << 2;
      u16x4 pk = { f2bf(v.x), f2bf(v.y), f2bf(v.z), f2bf(v.w) };
      *(u16x4*)&strip[wp * 256 + row * 16 + q0] = pk;
    }
    __syncthreads();
    float acc = 0.f;
#pragma unroll
    for (int wp = 0; wp < 14; ++wp) acc += bf2f(strip[wp * 256 + t]);
    avg3[((size_t)bc * 14 + hp) * 256 + t] = acc;
    const u16x8* so = (const u16x8*)strip;
    u16x8* go = (u16x8*)(xbf + ((size_t)bc * 196 + hp * 14) * 256);
    for (int i = t; i < 448; i += 256) go[i] = so[i];
  } else if (b < 3776) {
    int i = (b - 3584) * 256 + t;  // 192*256 float4s
    float4 v = reinterpret_cast<const float4*>(pw)[i];
    u16x4 pk = { f2bf(v.x), f2bf(v.y), f2bf(v.z), f2bf(v.w) };
    reinterpret_cast<u16x4*>(pwbf)[i] = pk;
  } else {
    float (*tile)[33] = (float(*)[33])smem;  // 4224 B
    int bid2 = b - 3776;
    int bx = bid2 % 24, by = bid2 / 24;
    int tx = t & 31, ty = t >> 5;
#pragma unroll
    for (int k = 0; k < 4; ++k)
      tile[ty + 8 * k][tx] = cw[(size_t)(by * 32 + ty + 8 * k) * 768 + bx * 32 + tx];
    __syncthreads();
#pragma unroll
    for (int k = 0; k < 4; ++k)
      cwT[(size_t)(bx * 32 + ty + 8 * k) * 768 + by * 32 + tx] = tile[tx][ty + 8 * k];
  }
}

// sp[s][k] = (sum over bc with seg[bc]==s, hp of avg3) / (196*max(cnt,1))
__global__ __launch_bounds__(256) void k_segmean(const float* __restrict__ avg3,
                                                 const int* __restrict__ seg,
                                                 float* __restrict__ sp) {
  __shared__ float red[4][64];
  __shared__ int rcnt[4];
  __shared__ int ssg[256];
  int s = blockIdx.x & 31, kc = blockIdx.x >> 5;
  int t = threadIdx.x;
  int kl = t & 63, slice = t >> 6;
  int k = kc * 64 + kl;
  ssg[t] = seg[t];
  __syncthreads();
  float sum = 0.f; int cnt = 0;
  for (int bc = slice * 64; bc < slice * 64 + 64; ++bc) {
    if (ssg[bc] == s) {
      ++cnt;
      const float* row = avg3 + (size_t)bc * 14 * 256 + k;
#pragma unroll
      for (int hp = 0; hp < 14; ++hp) sum += row[hp * 256];
    }
  }
  red[slice][kl] = sum;
  if (kl == 0) rcnt[slice] = cnt;
  __syncthreads();
  if (t < 64) {
    float tot = red[0][t] + red[1][t] + red[2][t] + red[3][t];
    int c = rcnt[0] + rcnt[1] + rcnt[2] + rcnt[3];
    sp[s * 256 + kc * 64 + t] = tot / (196.0f * (float)(c > 0 ? c : 1));
  }
}

// means[s][e] = sp[s] . pw[e] + pb[e]
__global__ __launch_bounds__(256) void k_means2(const float* __restrict__ sp,
                                                const float* __restrict__ pw,
                                                const float* __restrict__ pb,
                                                float* __restrict__ means) {
  __shared__ float ssp[256];
  __shared__ float red[8][32];
  int s = blockIdx.x & 31, e0 = (blockIdx.x >> 5) << 5;
  int t = threadIdx.x;
  int e = t & 31, ksl = t >> 5;
  ssp[t] = sp[s * 256 + t];
  __syncthreads();
  const float4* w = reinterpret_cast<const float4*>(pw + (size_t)(e0 + e) * 256 + ksl * 32);
  float a = 0.f;
#pragma unroll
  for (int j = 0; j < 8; ++j) {
    float4 v = w[j];
    int kb = ksl * 32 + j * 4;
    a += v.x * ssp[kb] + v.y * ssp[kb + 1] + v.z * ssp[kb + 2] + v.w * ssp[kb + 3];
  }
  red[ksl][e] = a;
  __syncthreads();
  if (t < 32) {
    float tot = 0.f;
#pragma unroll
    for (int j = 0; j < 8; ++j) tot += red[j][t];
    means[s * 768 + e0 + t] = tot + pb[e0 + t];
  }
}

// addv[s][e] = means[s] . cwT[:,e] + cb[e] + pb[e]
__global__ __launch_bounds__(256) void k_ctx2(const float* __restrict__ means,
                                              const float* __restrict__ cwT,
                                              const float* __restrict__ cb,
                                              const float* __restrict__ pb,
                                              float* __restrict__ addv) {
  __shared__ float mn[768];
  __shared__ float red[8][32];
  int s = blockIdx.x & 31, e0 = (blockIdx.x >> 5) << 5;
  int t = threadIdx.x;
  int e = t & 31, fsl = t >> 5;
  mn[t] = means[s * 768 + t];
  mn[t + 256] = means[s * 768 + 256 + t];
  mn[t + 512] = means[s * 768 + 512 + t];
  __syncthreads();
  const float* col = cwT + (size_t)fsl * 96 * 768 + e0 + e;
  float a = 0.f;
#pragma unroll 8
  for (int j = 0; j < 96; ++j) a += mn[fsl * 96 + j] * col[(size_t)j * 768];
  red[fsl][e] = a;
  __syncthreads();
  if (t < 32) {
    float tot = 0.f;
#pragma unroll
    for (int j = 0; j < 8; ++j) tot += red[j][t];
    addv[s * 768 + e0 + t] = tot + cb[e0 + t] + pb[e0 + t];
  }
}

// ---------------- main GEMM ----------------
// Swapped-operand MFMA: acc = mfma(W_frag, P_frag) so lane holds 4 CONSECUTIVE n
// -> epilogue is 16 dwordx4 stores instead of 64 scalar stores.
__global__ __launch_bounds__(256) void k_gemm(
    const unsigned short* __restrict__ xbf, const unsigned short* __restrict__ wbf,
    const float* __restrict__ addv, const int* __restrict__ seg,
    float* __restrict__ out) {
  __shared__ __align__(16) unsigned short Al[128 * 64];  // 16 KB
  __shared__ __align__(16) unsigned short Bl[128 * 64];  // 16 KB

  int bid = blockIdx.x;
  int xcd = bid & 7, local = bid >> 3;
  int mb = xcd * 49 + local / 6;
  int nb = local - (local / 6) * 6;
  int m0 = mb << 7, n0 = nb << 7;

  int t = threadIdx.x;
  int wave = t >> 6, lane = t & 63;
  int wm = (wave >> 1) << 6, wn = (wave & 1) << 6;
  int lr = lane & 15, hi = lane >> 4;
  int axor = (lr & 7) << 4;

  int swz = (((lane & 7) ^ ((lane >> 3) & 7)) << 4);
  const char* abase = (const char*)xbf + (size_t)(m0 + (lane >> 3)) * 512 + swz + (size_t)wave * 16384;
  const char* bbase = (const char*)wbf + (size_t)(n0 + (lane >> 3)) * 512 + swz + (size_t)wave * 16384;
  char* adst = (char*)Al + wave * 4096;
  char* bdst = (char*)Bl + wave * 4096;
  const char* Alc = (const char*)Al;
  const char* Blc = (const char*)Bl;

  f32x4 acc[4][4] = {};

  for (int kt = 0; kt < 4; ++kt) {
#pragma unroll
    for (int i = 0; i < 4; ++i) {
      gload16(abase + kt * 128 + i * 4096, adst + i * 1024);
      gload16(bbase + kt * 128 + i * 4096, bdst + i * 1024);
    }
    __syncthreads();
#pragma unroll
    for (int kk = 0; kk < 2; ++kk) {
      s16x8 af[4], bv[4];
      int koff = kk * 64 + hi * 16;
#pragma unroll
      for (int i = 0; i < 4; ++i)
        af[i] = *(const s16x8*)(Alc + (wm + i * 16 + lr) * 128 + (koff ^ axor));
#pragma unroll
      for (int j = 0; j < 4; ++j)
        bv[j] = *(const s16x8*)(Blc + (wn + j * 16 + lr) * 128 + (koff ^ axor));
      // swapped: D[row=n-local][col=patch]; af acts as B-frag (col=lane&15=patch),
      // bv acts as A-frag (row=lane&15=n-row). Same LDS reads as before.
#pragma unroll
      for (int i = 0; i < 4; ++i)
#pragma unroll
        for (int j = 0; j < 4; ++j)
          acc[i][j] = __builtin_amdgcn_mfma_f32_16x16x32_bf16(bv[j], af[i], acc[i][j], 0, 0, 0);
    }
    __syncthreads();
  }

  // epilogue: lane's acc[i][j] = C[m0+wm+i*16+lr][n0+wn+j*16+hi*4 .. +3]
#pragma unroll
  for (int i = 0; i < 4; ++i) {
    int M = m0 + wm + i * 16 + lr;
    int sgi = seg[M / 196];
    const float* av = addv + (size_t)sgi * 768 + n0 + wn + hi * 4;
    float* orow = out + (size_t)M * 768 + n0 + wn + hi * 4;
#pragma unroll
    for (int j = 0; j < 4; ++j) {
      f32x4 a4 = *(const f32x4*)(av + j * 16);
      f32x4 v = acc[i][j];
      v.x += a4.x; v.y += a4.y; v.z += a4.z; v.w += a4.w;
      *(f32x4*)(orow + j * 16) = v;
    }
  }
}

// ---------------- fallback path (if ws too small) ----------------
__global__ void k_cvt_fb(const float* __restrict__ in, unsigned short* __restrict__ o) {
  int i = blockIdx.x * 256 + threadIdx.x;
  float4 v = reinterpret_cast<const float4*>(in)[i];
  u16x4 pk = { f2bf(v.x), f2bf(v.y), f2bf(v.z), f2bf(v.w) };
  reinterpret_cast<u16x4*>(o)[i] = pk;
}

__global__ void k_transpose_fb(const float* __restrict__ in, float* __restrict__ out) {
  __shared__ float tile[32][33];
  int bx = blockIdx.x % 24, by = blockIdx.x / 24;
  int tx = threadIdx.x & 31, ty = threadIdx.x >> 5;
#pragma unroll
  for (int k = 0; k < 4; ++k)
    tile[ty + 8 * k][tx] = in[(size_t)(by * 32 + ty + 8 * k) * 768 + bx * 32 + tx];
  __syncthreads();
#pragma unroll
  for (int k = 0; k < 4; ++k)
    out[(size_t)(bx * 32 + ty + 8 * k) * 768 + by * 32 + tx] = tile[tx][ty + 8 * k];
}

__global__ void k_avgpatch_fb(const float* __restrict__ x, float* __restrict__ avg) {
  int bc = blockIdx.x;
  int k = threadIdx.x;
  int p = k >> 4, q = k & 15;
  const float* base = x + (size_t)bc * 224 * 224;
  float s = 0.f;
  for (int hp = 0; hp < 14; ++hp) {
    const float* row = base + (hp * 16 + p) * 224 + q;
#pragma unroll
    for (int wp = 0; wp < 14; ++wp) s += row[wp * 16];
  }
  avg[bc * 256 + k] = s * (1.0f / 196.0f);
}

__global__ __launch_bounds__(768) void k_chain_fb(const float* __restrict__ avg,
                                                  const int* __restrict__ seg,
                                                  const float* __restrict__ pw,
                                                  const float* __restrict__ pb,
                                                  const float* __restrict__ cwT,
                                                  const float* __restrict__ cb,
                                                  float* __restrict__ addv) {
  __shared__ float sp[256];
  __shared__ float mn[768];
  __shared__ int ssg[256];
  int s = blockIdx.x, t = threadIdx.x;
  if (t < 256) ssg[t] = seg[t];
  __syncthreads();
  if (t < 256) {
    float sum = 0.f; int c = 0;
    for (int bc = 0; bc < 256; ++bc)
      if (ssg[bc] == s) { sum += avg[bc * 256 + t]; ++c; }
    sp[t] = sum / (float)(c > 0 ? c : 1);
  }
  __syncthreads();
  {
    const float4* w = reinterpret_cast<const float4*>(pw + (size_t)t * 256);
    float a = 0.f;
#pragma unroll 8
    for (int k = 0; k < 64; ++k) {
      float4 v = w[k];
      a += v.x * sp[k * 4] + v.y * sp[k * 4 + 1] + v.z * sp[k * 4 + 2] + v.w * sp[k * 4 + 3];
    }
    mn[t] = a + pb[t];
  }
  __syncthreads();
  float a2 = 0.f;
#pragma unroll 8
  for (int f = 0; f < 768; ++f) a2 += mn[f] * cwT[(size_t)f * 768 + t];
  addv[s * 768 + t] = a2 + cb[t] + pb[t];
}

__global__ __launch_bounds__(256) void k_gemm_fb(
    const float* __restrict__ x, const unsigned short* __restrict__ wbf,
    const float* __restrict__ addv, const int* __restrict__ seg,
    float* __restrict__ out) {
  __shared__ unsigned short Al[128][40];
  __shared__ unsigned short Bl[128][40];
  int bid = blockIdx.x;
  int xcd = bid & 7, local = bid >> 3;
  int mb = xcd * 49 + local / 6;
  int nb = local - (local / 6) * 6;
  int m0 = mb << 7, n0 = nb << 7;
  int t = threadIdx.x;
  int wave = t >> 6, lane = t & 63;
  int wm = (wave >> 1) << 6, wn = (wave & 1) << 6;
  int lr = lane & 15, lk = (lane >> 4) << 3;
  int mstage = m0 + (t >> 1);
  int halfA = t & 1;
  int bc = mstage / 196;
  int pij = mstage - bc * 196;
  int hp = pij / 14;
  int wp = pij - hp * 14;
  const float* xbase = x + ((size_t)bc * 224 + hp * 16 + halfA) * 224 + wp * 16;
  const unsigned short* bsrc = wbf + (size_t)(n0 + (t >> 1)) * 256 + halfA * 16;
  unsigned short* adst = &Al[t >> 1][halfA * 16];
  unsigned short* bdst = &Bl[t >> 1][halfA * 16];
  f32x4 acc[4][4] = {};
  for (int ks = 0; ks < 8; ++ks) {
    __syncthreads();
    *(u16x8*)bdst       = *(const u16x8*)(bsrc + ks * 32);
    *(u16x8*)(bdst + 8) = *(const u16x8*)(bsrc + ks * 32 + 8);
    {
      const float4* src = reinterpret_cast<const float4*>(xbase + ks * 448);
      float4 v0 = src[0], v1 = src[1], v2 = src[2], v3 = src[3];
      u16x8 p0 = { f2bf(v0.x), f2bf(v0.y), f2bf(v0.z), f2bf(v0.w),
                   f2bf(v1.x), f2bf(v1.y), f2bf(v1.z), f2bf(v1.w) };
      u16x8 p1 = { f2bf(v2.x), f2bf(v2.y), f2bf(v2.z), f2bf(v2.w),
                   f2bf(v3.x), f2bf(v3.y), f2bf(v3.z), f2bf(v3.w) };
      *(u16x8*)adst = p0;
      *(u16x8*)(adst + 8) = p1;
    }
    __syncthreads();
    s16x8 af[4], bfv[4];
#pragma unroll
    for (int i = 0; i < 4; ++i) af[i] = *(const s16x8*)&Al[wm + i * 16 + lr][lk];
#pragma unroll
    for (int j = 0; j < 4; ++j) bfv[j] = *(const s16x8*)&Bl[wn + j * 16 + lr][lk];
#pragma unroll
    for (int i = 0; i < 4; ++i)
#pragma unroll
      for (int j = 0; j < 4; ++j)
        acc[i][j] = __builtin_amdgcn_mfma_f32_16x16x32_bf16(bfv[j], af[i], acc[i][j], 0, 0, 0);
  }
#pragma unroll
  for (int i = 0; i < 4; ++i) {
    int M = m0 + wm + i * 16 + lr;
    int sgi = seg[M / 196];
    int hi = lane >> 4;
    const float* av = addv + (size_t)sgi * 768 + n0 + wn + hi * 4;
    float* orow = out + (size_t)M * 768 + n0 + wn + hi * 4;
#pragma unroll
    for (int j = 0; j < 4; ++j) {
      f32x4 a4 = *(const f32x4*)(av + j * 16);
      f32x4 v = acc[i][j];
      v.x += a4.x; v.y += a4.y; v.z += a4.z; v.w += a4.w;
      *(f32x4*)(orow + j * 16) = v;
    }
  }
}

// ---------------- launch ----------------

extern "C" void kernel_launch(void* const* d_in, const int* in_sizes, int n_in,
                              void* d_out, int out_size, void* d_ws, size_t ws_size,
                              hipStream_t stream) {
  (void)in_sizes; (void)n_in; (void)out_size;
  const float* x  = (const float*)d_in[0];
  const int*   sg = (const int*)d_in[1];
  const float* pw = (const float*)d_in[2];
  const float* pb = (const float*)d_in[3];
  const float* cw = (const float*)d_in[4];
  const float* cb = (const float*)d_in[5];
  float* out = (float*)d_out;

  char* ws = (char*)d_ws;
  unsigned short* pwbf = (unsigned short*)ws;            // 393216 B
  float* cwT   = (float*)(ws + 393216);                  // 2359296 B
  float* addv  = (float*)(ws + 2752512);                 // 98304 B
  float* sp    = (float*)(ws + 2850816);                 // 32768 B
  float* means = (float*)(ws + 2883584);                 // 98304 B
  float* avg3  = (float*)(ws + 2981888);                 // 3670016 B
  unsigned short* xbf = (unsigned short*)(ws + 6651904); // 25690112 B
  const size_t NEED = 6651904u + 25690112u;              // 32.3 MB

  if (ws_size >= NEED) {
    k_mega<<<4352, 256, 0, stream>>>(x, xbf, avg3, pw, pwbf, cw, cwT);
    k_segmean<<<128, 256, 0, stream>>>(avg3, sg, sp);
    k_means2<<<768, 256, 0, stream>>>(sp, pw, pb, means);
    k_ctx2<<<768, 256, 0, stream>>>(means, cwT, cb, pb, addv);
    k_gemm<<<2352, 256, 0, stream>>>(xbf, pwbf, addv, sg, out);
  } else {
    float* avgp = (float*)(ws + 2981888);
    k_cvt_fb<<<192, 256, 0, stream>>>(pw, pwbf);
    k_transpose_fb<<<576, 256, 0, stream>>>(cw, cwT);
    k_avgpatch_fb<<<256, 256, 0, stream>>>(x, avgp);
    k_chain_fb<<<32, 768, 0, stream>>>(avgp, sg, pw, pb, cwT, cb, addv);
    k_gemm_fb<<<2352, 256, 0, stream>>>(x, pwbf, addv, sg, out);
  }
}